// Round 19
// baseline (248.055 us; speedup 1.0000x reference)
//
#include <hip/hip_runtime.h>
#include <hip/hip_bf16.h>
#include <math.h>

#define B_ 4
#define N_ 1024
#define C_ 768
#define H_ 12
#define D_ 64
#define TOPK_ 32
#define EPS_ 1e-9f

#define LDN_ 32   // linear LDS row stride (u16) for global_load_lds staging
#define LK_  72   // attn LDS row stride: 64 used + 8 pad = 144 B
#define QKS_ 1536 // Q,K plane row stride (elems)

typedef __attribute__((ext_vector_type(8))) short bf16x8;
typedef __attribute__((ext_vector_type(4))) float f32x4;
typedef unsigned short u16;

struct TopkRec { unsigned int cnt; unsigned short c[62]; };  // 128 B

__device__ __forceinline__ u16 f2bf(float f) {
    unsigned int u = __float_as_uint(f);
    u += 0x7fffu + ((u >> 16) & 1u);
    return (u16)(u >> 16);
}
__device__ __forceinline__ float bf2f(u16 h) {
    return __uint_as_float(((unsigned int)h) << 16);
}

// async global->LDS, 16B per lane; LDS dest is wave-uniform base + lane*16.
__device__ __forceinline__ void gll16(const void* g, void* l) {
    __builtin_amdgcn_global_load_lds(
        (const __attribute__((address_space(1))) void*)g,
        (__attribute__((address_space(3))) void*)l, 16, 0, 0);
}

// ---------------------------------------------------------------------------
// Fused conversions (one dispatch): blocks [0,1536) split x into hi/lo
// planes; blocks [1536,1968) transpose+split qkv_w.
// ---------------------------------------------------------------------------
__global__ __launch_bounds__(256) void conv_all(
    const float* __restrict__ X, u16* __restrict__ Xh, u16* __restrict__ Xl,
    const float* __restrict__ W, u16* __restrict__ Wt_h, u16* __restrict__ Wt_l)
{
    __shared__ float Ts[64][65];
    const int bid = blockIdx.x;
    const int t   = threadIdx.x;

    if (bid < 1536) {
        // ---- conv_x part: x f32 [4096][768] -> hi/lo planes
        const size_t off = ((size_t)bid * 256 + t) * 8;
        float4 a = *(const float4*)&X[off];
        float4 b = *(const float4*)&X[off + 4];
        float v[8] = {a.x, a.y, a.z, a.w, b.x, b.y, b.z, b.w};
        u16 hb[8], lb[8];
        #pragma unroll
        for (int i = 0; i < 8; ++i) {
            u16 hi = f2bf(v[i]);
            hb[i] = hi;
            lb[i] = f2bf(v[i] - bf2f(hi));
        }
        *(bf16x8*)&Xh[off] = *(const bf16x8*)&hb[0];
        *(bf16x8*)&Xl[off] = *(const bf16x8*)&lb[0];
    } else {
        // ---- conv_w part: qkv_w f32 [768][2304] -> transposed split planes
        const int wb = bid - 1536;        // 0..431 = 36 xt x 12 yt
        const int n0 = (wb % 36) * 64, k0 = (wb / 36) * 64;
        const int r  = t >> 2;
        const int cq = (t & 3) * 16;

        #pragma unroll
        for (int q = 0; q < 4; ++q) {
            float4 v = *(const float4*)&W[(size_t)(k0 + r) * 2304 + n0 + cq + q * 4];
            Ts[r][cq + q * 4 + 0] = v.x;
            Ts[r][cq + q * 4 + 1] = v.y;
            Ts[r][cq + q * 4 + 2] = v.z;
            Ts[r][cq + q * 4 + 3] = v.w;
        }
        __syncthreads();
        u16 hb[16], lb[16];
        #pragma unroll
        for (int i = 0; i < 16; ++i) {
            float val = Ts[cq + i][r];
            u16 hi = f2bf(val);
            hb[i] = hi;
            lb[i] = f2bf(val - bf2f(hi));
        }
        const size_t obase = (size_t)(n0 + r) * 768 + k0 + cq;
        *(bf16x8*)&Wt_h[obase]     = *(const bf16x8*)&hb[0];
        *(bf16x8*)&Wt_h[obase + 8] = *(const bf16x8*)&hb[8];
        *(bf16x8*)&Wt_l[obase]     = *(const bf16x8*)&lb[0];
        *(bf16x8*)&Wt_l[obase + 8] = *(const bf16x8*)&lb[8];
    }
}

// ---------------------------------------------------------------------------
// Weight convert: W f32 [K][Ncols] -> Wt_h, Wt_l bf16 [Ncols][K] transposed.
// (still used standalone for proj_w after z dies)
// ---------------------------------------------------------------------------
__global__ __launch_bounds__(256) void conv_w_nt(
    const float* __restrict__ W, u16* __restrict__ Wt_h, u16* __restrict__ Wt_l,
    int Kdim, int Ncols)
{
    __shared__ float Ts[64][65];
    const int t  = threadIdx.x;
    const int r  = t >> 2;
    const int cq = (t & 3) * 16;
    const int n0 = blockIdx.x * 64, k0 = blockIdx.y * 64;

    #pragma unroll
    for (int q = 0; q < 4; ++q) {
        float4 v = *(const float4*)&W[(size_t)(k0 + r) * Ncols + n0 + cq + q * 4];
        Ts[r][cq + q * 4 + 0] = v.x;
        Ts[r][cq + q * 4 + 1] = v.y;
        Ts[r][cq + q * 4 + 2] = v.z;
        Ts[r][cq + q * 4 + 3] = v.w;
    }
    __syncthreads();
    u16 hb[16], lb[16];
    #pragma unroll
    for (int i = 0; i < 16; ++i) {
        float val = Ts[cq + i][r];
        u16 hi = f2bf(val);
        hb[i] = hi;
        lb[i] = f2bf(val - bf2f(hi));
    }
    const size_t obase = (size_t)(n0 + r) * Kdim + k0 + cq;
    *(bf16x8*)&Wt_h[obase]     = *(const bf16x8*)&hb[0];
    *(bf16x8*)&Wt_h[obase + 8] = *(const bf16x8*)&hb[8];
    *(bf16x8*)&Wt_l[obase]     = *(const bf16x8*)&lb[0];
    *(bf16x8*)&Wt_l[obase + 8] = *(const bf16x8*)&lb[8];
}

// ---------------------------------------------------------------------------
// qkv GEMM: 128x128 tile, pure-plane NT, global_load_lds staging with
// COUNTED-vmcnt depth-1 double buffer, XCD swizzle, LDS-transposed epilogue.
// ---------------------------------------------------------------------------
__global__ __launch_bounds__(256) void gemm_qkv(
    const u16* __restrict__ Ath, const u16* __restrict__ Atl,
    const u16* __restrict__ Bth, const u16* __restrict__ Btl,
    const float* __restrict__ bias,
    u16* __restrict__ Ch, u16* __restrict__ Cl, float* __restrict__ Vf)
{
    __shared__ __align__(16) char smem[65536];   // 2 x 32KB staging buffers

    const int t    = threadIdx.x;
    // XCD swizzle: grid(576); 9 x-tiles x 8 y-tiles per XCD
    const int d    = blockIdx.x;
    const int xcd  = d & 7, j = d >> 3;
    const int xt   = (xcd & 1) * 9 + (j % 9);
    const int yt   = (xcd >> 1) * 8 + (j / 9);
    const int m0   = yt * 128, n0 = xt * 128;
    const int lane = t & 63, w = t >> 6;
    const int wm   = (w >> 1) * 64, wn = (w & 1) * 64;
    const int fr   = lane & 15, kg8 = lane >> 4;
    const int w16  = w * 16;
    const int r4s  = lane >> 2, q4s = (lane & 3) * 8;

    auto stage = [&](int k0, int buf) {
        char* base = smem + buf * 32768;
        u16* Ah = (u16*)(base);
        u16* Al = (u16*)(base + 8192);
        u16* Bh = (u16*)(base + 16384);
        u16* Bl = (u16*)(base + 24576);
        const size_t ga0 = (size_t)(m0 + w16 + r4s) * C_ + k0 + q4s;
        const size_t ga1 = ga0 + (size_t)64 * C_;
        const size_t gb0 = (size_t)(n0 + w16 + r4s) * C_ + k0 + q4s;
        const size_t gb1 = gb0 + (size_t)64 * C_;
        gll16(&Ath[ga0], &Ah[w16 * LDN_]);
        gll16(&Ath[ga1], &Ah[(64 + w16) * LDN_]);
        gll16(&Atl[ga0], &Al[w16 * LDN_]);
        gll16(&Atl[ga1], &Al[(64 + w16) * LDN_]);
        gll16(&Bth[gb0], &Bh[w16 * LDN_]);
        gll16(&Bth[gb1], &Bh[(64 + w16) * LDN_]);
        gll16(&Btl[gb0], &Bl[w16 * LDN_]);
        gll16(&Btl[gb1], &Bl[(64 + w16) * LDN_]);
    };

    f32x4 acc[4][4];
    #pragma unroll
    for (int i = 0; i < 4; ++i)
        #pragma unroll
        for (int j2 = 0; j2 < 4; ++j2)
            acc[i][j2] = (f32x4){0.f, 0.f, 0.f, 0.f};

    stage(0, 0);                          // 8 loads in flight
    for (int kt = 0; kt < 24; ++kt) {
        if (kt < 23) {
            asm volatile("s_waitcnt lgkmcnt(0)" ::: "memory");
            __builtin_amdgcn_s_barrier();
            __builtin_amdgcn_sched_barrier(0);
            stage((kt + 1) * 32, (kt + 1) & 1);          // +8 -> 16 in flight
            asm volatile("s_waitcnt vmcnt(8)" ::: "memory"); // stage(kt) done
        } else {
            asm volatile("s_waitcnt vmcnt(0)" ::: "memory");
        }
        __builtin_amdgcn_s_barrier();     // all waves' stage(kt) visible
        __builtin_amdgcn_sched_barrier(0);

        char* base = smem + (kt & 1) * 32768;
        u16* Ah = (u16*)(base);
        u16* Al = (u16*)(base + 8192);
        u16* Bh = (u16*)(base + 16384);
        u16* Bl = (u16*)(base + 24576);

        bf16x8 aF[4], bF[4], a2F[4], b2F[4];
        #pragma unroll
        for (int fm = 0; fm < 4; ++fm)
            aF[fm] = *(const bf16x8*)&Ah[(wm + fm * 16 + fr) * LDN_ + kg8 * 8];
        #pragma unroll
        for (int fn = 0; fn < 4; ++fn)
            bF[fn] = *(const bf16x8*)&Bh[(wn + fn * 16 + fr) * LDN_ + kg8 * 8];
        #pragma unroll
        for (int fm = 0; fm < 4; ++fm)
            #pragma unroll
            for (int fn = 0; fn < 4; ++fn)
                acc[fm][fn] = __builtin_amdgcn_mfma_f32_16x16x32_bf16(
                    aF[fm], bF[fn], acc[fm][fn], 0, 0, 0);
        #pragma unroll
        for (int fn = 0; fn < 4; ++fn)
            b2F[fn] = *(const bf16x8*)&Bl[(wn + fn * 16 + fr) * LDN_ + kg8 * 8];
        #pragma unroll
        for (int fm = 0; fm < 4; ++fm)
            #pragma unroll
            for (int fn = 0; fn < 4; ++fn)
                acc[fm][fn] = __builtin_amdgcn_mfma_f32_16x16x32_bf16(
                    aF[fm], b2F[fn], acc[fm][fn], 0, 0, 0);
        #pragma unroll
        for (int fm = 0; fm < 4; ++fm)
            a2F[fm] = *(const bf16x8*)&Al[(wm + fm * 16 + fr) * LDN_ + kg8 * 8];
        #pragma unroll
        for (int fm = 0; fm < 4; ++fm)
            #pragma unroll
            for (int fn = 0; fn < 4; ++fn)
                acc[fm][fn] = __builtin_amdgcn_mfma_f32_16x16x32_bf16(
                    a2F[fm], bF[fn], acc[fm][fn], 0, 0, 0);
    }
    __syncthreads();   // full drain; staging LDS reusable for epilogue

    // Epilogue: per-wave LDS transpose -> coalesced vector stores.
    const bool isV = (n0 >= 1536);
    float* Ts = (float*)(smem + w * 8448);   // 32 x 66 f32 per wave
    const int lr8 = lane >> 3, lc8 = (lane & 7) * 8;
    #pragma unroll
    for (int p = 0; p < 2; ++p) {
        #pragma unroll
        for (int fmh = 0; fmh < 2; ++fmh) {
            const int fm = p * 2 + fmh;
            #pragma unroll
            for (int fn = 0; fn < 4; ++fn) {
                const float bv = bias[n0 + wn + fn * 16 + fr];
                #pragma unroll
                for (int i = 0; i < 4; ++i)
                    Ts[(fmh * 16 + kg8 * 4 + i) * 66 + fn * 16 + fr] =
                        acc[fm][fn][i] + bv;
            }
        }
        #pragma unroll
        for (int it = 0; it < 4; ++it) {
            const int r = it * 8 + lr8;
            float v[8];
            #pragma unroll
            for (int c = 0; c < 8; ++c) v[c] = Ts[r * 66 + lc8 + c];
            const int grow = m0 + wm + p * 32 + r;
            const int gcol = n0 + wn + lc8;
            if (isV) {
                float4 v0 = {v[0], v[1], v[2], v[3]};
                float4 v1 = {v[4], v[5], v[6], v[7]};
                float* vp = &Vf[(size_t)grow * C_ + gcol - 1536];
                *(float4*)vp       = v0;
                *(float4*)(vp + 4) = v1;
            } else {
                u16 hb[8], lb[8];
                #pragma unroll
                for (int c = 0; c < 8; ++c) {
                    u16 hi = f2bf(v[c]);
                    hb[c] = hi;
                    lb[c] = f2bf(v[c] - bf2f(hi));
                }
                *(bf16x8*)&Ch[(size_t)grow * QKS_ + gcol] = *(const bf16x8*)&hb[0];
                *(bf16x8*)&Cl[(size_t)grow * QKS_ + gcol] = *(const bf16x8*)&lb[0];
            }
        }
    }
}

// ---------------------------------------------------------------------------
// Fused z + per-head partial softmax, T14 async-stage pipelined over heads.
// Unstabilized softmax (scores O(1)), fast __expf/__logf.
// ---------------------------------------------------------------------------
__global__ __launch_bounds__(256) void attn_fused(
    const u16* __restrict__ qh, const u16* __restrict__ ql,
    const float* __restrict__ u, float* __restrict__ z,
    float2* __restrict__ mlp)
{
    __shared__ u16 KsH[128 * LK_], KsL[128 * LK_];

    const int t    = threadIdx.x;
    const int lane = t & 63, w = t >> 6;
    const int fr   = lane & 15, kg8 = lane >> 4;
    const int n0   = blockIdx.x * 64;
    const int m0   = blockIdx.y * 128;
    const int mc   = blockIdx.y;
    const int b    = blockIdx.z;

    f32x4 zacc[8];
    #pragma unroll
    for (int fn = 0; fn < 8; ++fn) zacc[fn] = (f32x4){0.f, 0.f, 0.f, 0.f};

    const int skr = t >> 1, skd = (t & 1) * 32;

    bf16x8 kAr[8], kBr[8], qAr[4], qBr[4];

    auto loadK = [&](bf16x8 (&kr)[8], int hd) {
        const size_t kb = (size_t)(b * N_ + m0 + skr) * QKS_ + 768 + hd * 64 + skd;
        kr[0] = *(const bf16x8*)&qh[kb];
        kr[1] = *(const bf16x8*)&qh[kb + 8];
        kr[2] = *(const bf16x8*)&qh[kb + 16];
        kr[3] = *(const bf16x8*)&qh[kb + 24];
        kr[4] = *(const bf16x8*)&ql[kb];
        kr[5] = *(const bf16x8*)&ql[kb + 8];
        kr[6] = *(const bf16x8*)&ql[kb + 16];
        kr[7] = *(const bf16x8*)&ql[kb + 24];
    };
    auto loadQ = [&](bf16x8 (&qr)[4], int hd) {
        const size_t qb = (size_t)(b * N_ + n0 + w * 16 + fr) * QKS_ + hd * 64 + kg8 * 8;
        qr[0] = *(const bf16x8*)&qh[qb];
        qr[1] = *(const bf16x8*)&qh[qb + 32];
        qr[2] = *(const bf16x8*)&ql[qb];
        qr[3] = *(const bf16x8*)&ql[qb + 32];
    };
    auto writeK = [&](const bf16x8 (&kr)[8]) {
        const int sb = skr * LK_ + skd;
        *(bf16x8*)&KsH[sb]      = kr[0];  *(bf16x8*)&KsH[sb + 8]  = kr[1];
        *(bf16x8*)&KsH[sb + 16] = kr[2];  *(bf16x8*)&KsH[sb + 24] = kr[3];
        *(bf16x8*)&KsL[sb]      = kr[4];  *(bf16x8*)&KsL[sb + 8]  = kr[5];
        *(bf16x8*)&KsL[sb + 16] = kr[6];  *(bf16x8*)&KsL[sb + 24] = kr[7];
    };
    auto compute = [&](const bf16x8 (&qr)[4], int hd) {
        f32x4 acc[8];
        #pragma unroll
        for (int fn = 0; fn < 8; ++fn) acc[fn] = (f32x4){0.f, 0.f, 0.f, 0.f};
        #pragma unroll
        for (int fn = 0; fn < 8; ++fn) {
            const int bidx = (fn * 16 + fr) * LK_ + kg8 * 8;
            bf16x8 bH = *(const bf16x8*)&KsH[bidx];
            bf16x8 bL = *(const bf16x8*)&KsL[bidx];
            acc[fn] = __builtin_amdgcn_mfma_f32_16x16x32_bf16(qr[0], bH, acc[fn], 0, 0, 0);
            acc[fn] = __builtin_amdgcn_mfma_f32_16x16x32_bf16(qr[0], bL, acc[fn], 0, 0, 0);
            acc[fn] = __builtin_amdgcn_mfma_f32_16x16x32_bf16(qr[2], bH, acc[fn], 0, 0, 0);
        }
        #pragma unroll
        for (int fn = 0; fn < 8; ++fn) {
            const int bidx = (fn * 16 + fr) * LK_ + 32 + kg8 * 8;
            bf16x8 bH = *(const bf16x8*)&KsH[bidx];
            bf16x8 bL = *(const bf16x8*)&KsL[bidx];
            acc[fn] = __builtin_amdgcn_mfma_f32_16x16x32_bf16(qr[1], bH, acc[fn], 0, 0, 0);
            acc[fn] = __builtin_amdgcn_mfma_f32_16x16x32_bf16(qr[1], bL, acc[fn], 0, 0, 0);
            acc[fn] = __builtin_amdgcn_mfma_f32_16x16x32_bf16(qr[3], bH, acc[fn], 0, 0, 0);
        }
        #pragma unroll
        for (int fn = 0; fn < 8; ++fn) {
            zacc[fn][0] += acc[fn][0];
            zacc[fn][1] += acc[fn][1];
            zacc[fn][2] += acc[fn][2];
            zacc[fn][3] += acc[fn][3];
        }
        #pragma unroll
        for (int reg = 0; reg < 4; ++reg) {
            float tsum = 0.f;
            #pragma unroll
            for (int fn = 0; fn < 8; ++fn)
                tsum += __expf(acc[fn][reg] * 0.125f);
            tsum += __shfl_xor(tsum, 1);
            tsum += __shfl_xor(tsum, 2);
            tsum += __shfl_xor(tsum, 4);
            tsum += __shfl_xor(tsum, 8);
            if (fr == 0) {
                const int n = n0 + w * 16 + kg8 * 4 + reg;
                mlp[(((size_t)(b * H_ + hd)) * N_ + n) * 8 + mc] =
                    make_float2(0.f, tsum);
            }
        }
    };

    loadQ(qAr, 0);
    loadK(kAr, 0);
    for (int hp = 0; hp < 6; ++hp) {
        const int hd0 = hp * 2, hd1 = hp * 2 + 1;
        __syncthreads();
        writeK(kAr);
        __syncthreads();
        loadQ(qBr, hd1);
        loadK(kBr, hd1);
        compute(qAr, hd0);
        __syncthreads();
        writeK(kBr);
        __syncthreads();
        if (hp < 5) {
            loadQ(qAr, hd0 + 2);
            loadK(kAr, hd0 + 2);
        }
        compute(qBr, hd1);
    }

    const float sc = 0.125f / 12.0f;
    #pragma unroll
    for (int fn = 0; fn < 8; ++fn) {
        const int m = m0 + fn * 16 + fr;
        #pragma unroll
        for (int reg = 0; reg < 4; ++reg) {
            const int n = n0 + w * 16 + kg8 * 4 + reg;
            const float uv = u[((size_t)(b * N_ + n)) * N_ + m];
            const float g  = -__logf(-__logf(uv + EPS_) + EPS_);
            z[((size_t)(b * N_ + n)) * N_ + m] = zacc[fn][reg] * sc + g;
        }
    }
}

// ---------------------------------------------------------------------------
// Per row: exact 32nd-largest of z; emit all cols >= thresh (cap 62).
// ---------------------------------------------------------------------------
__global__ __launch_bounds__(64) void topk_cols_kernel(
    const float* __restrict__ z, TopkRec* __restrict__ recs)
{
    const int row  = blockIdx.x;
    const int lane = threadIdx.x;
    const float* zr = z + (size_t)row * N_;
    float zv[16], wk[16];
    #pragma unroll
    for (int j = 0; j < 16; ++j) { zv[j] = zr[lane + 64 * j]; wk[j] = zv[j]; }

    float thresh = -INFINITY;
    for (int it = 0; it < TOPK_; ++it) {
        float lm = wk[0]; int li = 0;
        #pragma unroll
        for (int j = 1; j < 16; ++j)
            if (wk[j] > lm) { lm = wk[j]; li = j; }
        float gm = lm;
        gm = fmaxf(gm, __shfl_xor(gm, 1));
        gm = fmaxf(gm, __shfl_xor(gm, 2));
        gm = fmaxf(gm, __shfl_xor(gm, 4));
        gm = fmaxf(gm, __shfl_xor(gm, 8));
        gm = fmaxf(gm, __shfl_xor(gm, 16));
        gm = fmaxf(gm, __shfl_xor(gm, 32));
        unsigned long long has = __ballot(lm == gm);
        int first = __ffsll((unsigned long long)has) - 1;
        if (lane == first) wk[li] = -INFINITY;
        thresh = gm;
    }

    const unsigned long long below = ((unsigned long long)1 << lane) - 1;
    unsigned int basec = 0;
    TopkRec* rec = recs + row;
    #pragma unroll
    for (int j = 0; j < 16; ++j) {
        unsigned long long wmask = __ballot(zv[j] >= thresh);
        if (zv[j] >= thresh) {
            unsigned int pos = basec + (unsigned int)__popcll(wmask & below);
            if (pos < 62u) rec->c[pos] = (unsigned short)(lane + 64 * j);
        }
        basec += (unsigned int)__popcll(wmask);
    }
    if (lane == 0) rec->cnt = basec > 62u ? 62u : basec;
}

// ---------------------------------------------------------------------------
// Pass B: sparse gather numerator. Lane = (c,dq). V read as f32.
// Batch-pair ILP + XCD-locality swizzle. ml_merge is INLINED: denominator
// l computed directly from the 8 per-chunk partial sums in mlp.
// ---------------------------------------------------------------------------
__global__ __launch_bounds__(256) void sparse_pv_kernel(
    const u16* __restrict__ qh, const u16* __restrict__ ql,
    const float* __restrict__ Vf,
    const TopkRec* __restrict__ recs, const float2* __restrict__ mlp,
    const float* __restrict__ head_scores,
    u16* __restrict__ out1h, u16* __restrict__ out1l)
{
    __shared__ int cols_s[62];
    __shared__ int cnt_s;

    const int t    = threadIdx.x;
    const int lane = t & 63, wv = t >> 6;
    const int c4   = lane >> 2;
    const int dq   = lane & 3;
    // XCD-locality: d -> (b, n) so batch b lands on XCDs {2b, 2b+1}
    const int d    = blockIdx.x;
    const int xcd  = d & 7;
    const int b    = xcd >> 1;
    const int n    = (xcd & 1) * 512 + (d >> 3);
    const int row  = b * N_ + n;

    const TopkRec* rec = recs + row;
    if (t == 0) cnt_s = (int)min(rec->cnt, 62u);
    if (t < 62) cols_s[t] = rec->c[t];

    float hsum = 0.f;
    #pragma unroll
    for (int i = 0; i < H_; ++i) hsum += head_scores[i];
    const float hs_mean = hsum * (1.0f / 12.0f);
    __syncthreads();
    const int cnt = cnt_s;
    const int nbatch = (cnt + 15) >> 4;

    for (int hd = wv; hd < H_; hd += 4) {
        float qv[16];
        {
            const size_t qb = (size_t)row * QKS_ + hd * 64 + dq * 16;
            bf16x8 qh0 = *(const bf16x8*)&qh[qb], qh1 = *(const bf16x8*)&qh[qb + 8];
            bf16x8 ql0 = *(const bf16x8*)&ql[qb], ql1 = *(const bf16x8*)&ql[qb + 8];
            #pragma unroll
            for (int i = 0; i < 8; ++i) {
                qv[i]     = bf2f((u16)qh0[i]) + bf2f((u16)ql0[i]);
                qv[i + 8] = bf2f((u16)qh1[i]) + bf2f((u16)ql1[i]);
            }
        }
        // inline ml_merge: l = sum of 8 per-chunk partial sums
        float lsum = 0.f;
        {
            const size_t mb = (((size_t)(b * H_ + hd)) * N_ + n) * 8;
            #pragma unroll
            for (int i = 0; i < 8; ++i) lsum += mlp[mb + i].y;
        }

        float acc[16];
        #pragma unroll
        for (int i = 0; i < 16; ++i) acc[i] = 0.f;

        for (int j0 = 0; j0 < nbatch; j0 += 2) {
            const int cidx0 = j0 * 16 + c4;
            const int cidx1 = cidx0 + 16;
            const bool v0 = (cidx0 < cnt);
            const bool v1 = (cidx1 < cnt);
            const int col0 = cols_s[v0 ? cidx0 : 0];
            const int col1 = cols_s[v1 ? cidx1 : 0];

            const size_t kb0 = (size_t)(b * N_ + col0) * QKS_ + 768 + hd * 64 + dq * 16;
            const size_t kb1 = (size_t)(b * N_ + col1) * QKS_ + 768 + hd * 64 + dq * 16;
            bf16x8 kh00 = *(const bf16x8*)&qh[kb0], kh01 = *(const bf16x8*)&qh[kb0 + 8];
            bf16x8 kl00 = *(const bf16x8*)&ql[kb0], kl01 = *(const bf16x8*)&ql[kb0 + 8];
            bf16x8 kh10 = *(const bf16x8*)&qh[kb1], kh11 = *(const bf16x8*)&qh[kb1 + 8];
            bf16x8 kl10 = *(const bf16x8*)&ql[kb1], kl11 = *(const bf16x8*)&ql[kb1 + 8];
            const float* vb0 = &Vf[(size_t)(b * N_ + col0) * C_ + hd * 64 + dq * 16];
            const float* vb1 = &Vf[(size_t)(b * N_ + col1) * C_ + hd * 64 + dq * 16];
            float4 va0[4], va1[4];
            #pragma unroll
            for (int q = 0; q < 4; ++q) {
                va0[q] = *(const float4*)&vb0[q * 4];
                va1[q] = *(const float4*)&vb1[q * 4];
            }

            float dot0 = 0.f, dot1 = 0.f;
            #pragma unroll
            for (int i = 0; i < 8; ++i) {
                dot0 += qv[i]     * (bf2f((u16)kh00[i]) + bf2f((u16)kl00[i]));
                dot1 += qv[i]     * (bf2f((u16)kh10[i]) + bf2f((u16)kl10[i]));
                dot0 += qv[i + 8] * (bf2f((u16)kh01[i]) + bf2f((u16)kl01[i]));
                dot1 += qv[i + 8] * (bf2f((u16)kh11[i]) + bf2f((u16)kl11[i]));
            }
            dot0 += __shfl_xor(dot0, 1);
            dot1 += __shfl_xor(dot1, 1);
            dot0 += __shfl_xor(dot0, 2);
            dot1 += __shfl_xor(dot1, 2);
            const float p0 = v0 ? __expf(dot0 * 0.125f) : 0.f;
            const float p1 = v1 ? __expf(dot1 * 0.125f) : 0.f;

            #pragma unroll
            for (int q = 0; q < 4; ++q) {
                acc[q * 4 + 0] += p0 * va0[q].x + p1 * va1[q].x;
                acc[q * 4 + 1] += p0 * va0[q].y + p1 * va1[q].y;
                acc[q * 4 + 2] += p0 * va0[q].z + p1 * va1[q].z;
                acc[q * 4 + 3] += p0 * va0[q].w + p1 * va1[q].w;
            }
        }

        #pragma unroll
        for (int dd = 4; dd < 64; dd <<= 1)
            #pragma unroll
            for (int i = 0; i < 16; ++i)
                acc[i] += __shfl_xor(acc[i], dd);

        if (c4 == 0) {
            const float s = hs_mean / lsum;
            u16 hb[16], lb[16];
            #pragma unroll
            for (int i = 0; i < 16; ++i) {
                float val = acc[i] * s;
                u16 hi = f2bf(val);
                hb[i] = hi;
                lb[i] = f2bf(val - bf2f(hi));
            }
            const size_t ob = (size_t)row * C_ + hd * 64 + dq * 16;
            *(bf16x8*)&out1h[ob]     = *(const bf16x8*)&hb[0];
            *(bf16x8*)&out1h[ob + 8] = *(const bf16x8*)&hb[8];
            *(bf16x8*)&out1l[ob]     = *(const bf16x8*)&lb[0];
            *(bf16x8*)&out1l[ob + 8] = *(const bf16x8*)&lb[8];
        }
    }
}

// ---------------------------------------------------------------------------
// proj GEMM: 64x128 tile (grid 384), pure-plane NT, counted-vmcnt depth-1
// double buffer, XCD swizzle, LDS-transposed coalesced f32 epilogue.
// ---------------------------------------------------------------------------
__global__ __launch_bounds__(256) void gemm_proj(
    const u16* __restrict__ Ath, const u16* __restrict__ Atl,
    const u16* __restrict__ Bth, const u16* __restrict__ Btl,
    const float* __restrict__ bias, float* __restrict__ Cm)
{
    __shared__ __align__(16) char smem[49152];   // 2 x 24KB staging buffers

    const int t    = threadIdx.x;
    // XCD swizzle: grid(384) = 6 xt x 64 yt; per XCD 6x x 8y
    const int d    = blockIdx.x;
    const int xcd  = d & 7, j = d >> 3;
    const int xt   = j % 6;
    const int yt   = xcd * 8 + j / 6;
    const int m0   = yt * 64, n0 = xt * 128;
    const int lane = t & 63, w = t >> 6;
    const int wm   = (w & 1) * 32, wn = (w >> 1) * 64;
    const int fr   = lane & 15, kg8 = lane >> 4;
    const int w16  = w * 16;
    const int r4s  = lane >> 2, q4s = (lane & 3) * 8;

    auto stage = [&](int k0, int buf) {
        char* base = smem + buf * 24576;
        u16* Ah = (u16*)(base);
        u16* Al = (u16*)(base + 4096);
        u16* Bh = (u16*)(base + 8192);
        u16* Bl = (u16*)(base + 16384);
        const size_t ga  = (size_t)(m0 + w16 + r4s) * C_ + k0 + q4s;
        const size_t gb0 = (size_t)(n0 + w * 32 + r4s) * C_ + k0 + q4s;
        const size_t gb1 = gb0 + (size_t)16 * C_;
        gll16(&Ath[ga],  &Ah[w16 * LDN_]);
        gll16(&Atl[ga],  &Al[w16 * LDN_]);
        gll16(&Bth[gb0], &Bh[(w * 32) * LDN_]);
        gll16(&Bth[gb1], &Bh[(w * 32 + 16) * LDN_]);
        gll16(&Btl[gb0], &Bl[(w * 32) * LDN_]);
        gll16(&Btl[gb1], &Bl[(w * 32 + 16) * LDN_]);
    };

    f32x4 acc[2][4];
    #pragma unroll
    for (int i = 0; i < 2; ++i)
        #pragma unroll
        for (int j2 = 0; j2 < 4; ++j2)
            acc[i][j2] = (f32x4){0.f, 0.f, 0.f, 0.f};

    stage(0, 0);
    for (int kt = 0; kt < 24; ++kt) {
        if (kt < 23) {
            asm volatile("s_waitcnt lgkmcnt(0)" ::: "memory");
            __builtin_amdgcn_s_barrier();
            __builtin_amdgcn_sched_barrier(0);
            stage((kt + 1) * 32, (kt + 1) & 1);
            asm volatile("s_waitcnt vmcnt(6)" ::: "memory");
        } else {
            asm volatile("s_waitcnt vmcnt(0)" ::: "memory");
        }
        __builtin_amdgcn_s_barrier();
        __builtin_amdgcn_sched_barrier(0);

        char* base = smem + (kt & 1) * 24576;
        u16* Ah = (u16*)(base);
        u16* Al = (u16*)(base + 4096);
        u16* Bh = (u16*)(base + 8192);
        u16* Bl = (u16*)(base + 16384);

        bf16x8 aF[2], bF[4], a2F[2], b2F[4];
        #pragma unroll
        for (int fm = 0; fm < 2; ++fm)
            aF[fm] = *(const bf16x8*)&Ah[(wm + fm * 16 + fr) * LDN_ + kg8 * 8];
        #pragma unroll
        for (int fn = 0; fn < 4; ++fn)
            bF[fn] = *(const bf16x8*)&Bh[(wn + fn * 16 + fr) * LDN_ + kg8 * 8];
        #pragma unroll
        for (int fm = 0; fm < 2; ++fm)
            #pragma unroll
            for (int fn = 0; fn < 4; ++fn)
                acc[fm][fn] = __builtin_amdgcn_mfma_f32_16x16x32_bf16(
                    aF[fm], bF[fn], acc[fm][fn], 0, 0, 0);
        #pragma unroll
        for (int fn = 0; fn < 4; ++fn)
            b2F[fn] = *(const bf16x8*)&Bl[(wn + fn * 16 + fr) * LDN_ + kg8 * 8];
        #pragma unroll
        for (int fm = 0; fm < 2; ++fm)
            #pragma unroll
            for (int fn = 0; fn < 4; ++fn)
                acc[fm][fn] = __builtin_amdgcn_mfma_f32_16x16x32_bf16(
                    aF[fm], b2F[fn], acc[fm][fn], 0, 0, 0);
        #pragma unroll
        for (int fm = 0; fm < 2; ++fm)
            a2F[fm] = *(const bf16x8*)&Al[(wm + fm * 16 + fr) * LDN_ + kg8 * 8];
        #pragma unroll
        for (int fm = 0; fm < 2; ++fm)
            #pragma unroll
            for (int fn = 0; fn < 4; ++fn)
                acc[fm][fn] = __builtin_amdgcn_mfma_f32_16x16x32_bf16(
                    a2F[fm], bF[fn], acc[fm][fn], 0, 0, 0);
    }
    __syncthreads();

    float* Ts = (float*)(smem + w * 8448);
    const int lr8 = lane >> 3, lc8 = (lane & 7) * 8;
    #pragma unroll
    for (int fm = 0; fm < 2; ++fm)
        #pragma unroll
        for (int fn = 0; fn < 4; ++fn) {
            const float bv = bias[n0 + wn + fn * 16 + fr];
            #pragma unroll
            for (int i = 0; i < 4; ++i)
                Ts[(fm * 16 + kg8 * 4 + i) * 66 + fn * 16 + fr] =
                    acc[fm][fn][i] + bv;
        }
    #pragma unroll
    for (int it = 0; it < 4; ++it) {
        const int r = it * 8 + lr8;
        float v[8];
        #pragma unroll
        for (int c = 0; c < 8; ++c) v[c] = Ts[r * 66 + lc8 + c];
        const int grow = m0 + wm + r;
        const int gcol = n0 + wn + lc8;
        float4 v0 = {v[0], v[1], v[2], v[3]};
        float4 v1 = {v[4], v[5], v[6], v[7]};
        float* cp = &Cm[(size_t)grow * C_ + gcol];
        *(float4*)cp       = v0;
        *(float4*)(cp + 4) = v1;
    }
}

// ---------------------------------------------------------------------------
extern "C" void kernel_launch(void* const* d_in, const int* in_sizes, int n_in,
                              void* d_out, int out_size, void* d_ws, size_t ws_size,
                              hipStream_t stream)
{
    (void)in_sizes; (void)n_in; (void)out_size; (void)ws_size;
    const float* x           = (const float*)d_in[0];
    const float* u           = (const float*)d_in[1];
    const float* qkv_w       = (const float*)d_in[2];
    const float* qkv_b       = (const float*)d_in[3];
    const float* proj_w      = (const float*)d_in[4];
    const float* proj_b      = (const float*)d_in[5];
    const float* head_scores = (const float*)d_in[6];
    float* out = (float*)d_out;

    // Workspace (proven 55,050,240-byte footprint):
    //   [0, 12582912)            qkv_h  bf16 [4096][1536]  (Q,K planes)
    //   [12582912, 25165824)     qkv_l
    //   [25165824, 37748736)     V f32 [4096][768]
    //   R = [37748736, 55050240), time-shared:
    //     phase1: wq_t_h | wq_t_l (dead after gemm_qkv)
    //     phase2: z f32 [0,16777216) + recs [16777216,17301504)
    //     phase3 (z dead): wp_t_h | wp_t_l | out1_h | out1_l
    // d_out (12,582,912 B) time-shared:
    //     x_h | x_l planes (dead after gemm_qkv)
    //     mlp partials [0, 3145728) (read by sparse_pv); gemm_proj
    //     overwrites d_out last.
    char* ws = (char*)d_ws;
    u16*     qkv_h  = (u16*)ws;
    u16*     qkv_l  = (u16*)(ws + 12582912);
    float*   Vf     = (float*)(ws + 25165824);
    char*    R      = ws + 37748736;
    u16*     wq_t_h = (u16*)R;
    u16*     wq_t_l = (u16*)(R + 3538944);
    float*   z      = (float*)R;
    TopkRec* recs   = (TopkRec*)(R + 16777216);
    u16*     wp_t_h = (u16*)R;
    u16*     wp_t_l = (u16*)(R + 1179648);
    u16*     out1h  = (u16*)(R + 2752512);
    u16*     out1l  = (u16*)(R + 9043968);
    u16*     x_h    = (u16*)d_out;
    u16*     x_l    = (u16*)((char*)d_out + 6291456);
    float2*  mlp    = (float2*)d_out;

    // 0+1) fused: pre-split x AND convert qkv_w (one dispatch)
    conv_all<<<dim3(1968), dim3(256), 0, stream>>>(
        x, x_h, x_l, qkv_w, wq_t_h, wq_t_l);

    // 2) qkv = x @ qkv_w + b  -> Q,K planes + V f32 (counted-vmcnt dbuf)
    gemm_qkv<<<dim3(576), dim3(256), 0, stream>>>(
        x_h, x_l, wq_t_h, wq_t_l, qkv_b, qkv_h, qkv_l, Vf);

    // 3) fused: z (+gumbel) AND per-head per-chunk softmax partials
    attn_fused<<<dim3(16, 8, B_), dim3(256), 0, stream>>>(
        qkv_h, qkv_l, u, z, mlp);

    // 4) exact top-32 -> column records
    topk_cols_kernel<<<dim3(B_ * N_), dim3(64), 0, stream>>>(z, recs);

    // 5) convert proj_w -> transposed split planes [768][768]  (z dead)
    conv_w_nt<<<dim3(768 / 64, 768 / 64), dim3(256), 0, stream>>>(
        proj_w, wp_t_h, wp_t_l, 768, 768);

    // 6) sparse gather numerator -> out1 planes (ml_merge inlined)
    sparse_pv_kernel<<<dim3(B_ * N_), dim3(256), 0, stream>>>(
        qkv_h, qkv_l, Vf, recs, mlp, head_scores, out1h, out1l);

    // 7) out = out1 @ proj_w + b  (counted-vmcnt dbuf)
    gemm_proj<<<dim3(384), dim3(256), 0, stream>>>(
        out1h, out1l, wp_t_h, wp_t_l, proj_b, out);
}

// Round 20
// 239.988 us; speedup vs baseline: 1.0336x; 1.0336x over previous
//
#include <hip/hip_runtime.h>
#include <hip/hip_bf16.h>
#include <math.h>

#define B_ 4
#define N_ 1024
#define C_ 768
#define H_ 12
#define D_ 64
#define TOPK_ 32
#define EPS_ 1e-9f

#define LDN_ 32   // linear LDS row stride (u16) for global_load_lds staging
#define LK_  72   // attn LDS row stride: 64 used + 8 pad = 144 B
#define QKS_ 1536 // Q,K plane row stride (elems)

typedef __attribute__((ext_vector_type(8))) short bf16x8;
typedef __attribute__((ext_vector_type(4))) float f32x4;
typedef unsigned short u16;

struct TopkRec { unsigned int cnt; unsigned short c[62]; };  // 128 B

__device__ __forceinline__ u16 f2bf(float f) {
    unsigned int u = __float_as_uint(f);
    u += 0x7fffu + ((u >> 16) & 1u);
    return (u16)(u >> 16);
}
__device__ __forceinline__ float bf2f(u16 h) {
    return __uint_as_float(((unsigned int)h) << 16);
}

// async global->LDS, 16B per lane; LDS dest is wave-uniform base + lane*16.
__device__ __forceinline__ void gll16(const void* g, void* l) {
    __builtin_amdgcn_global_load_lds(
        (const __attribute__((address_space(1))) void*)g,
        (__attribute__((address_space(3))) void*)l, 16, 0, 0);
}

// ---------------------------------------------------------------------------
// Fused conversions (one dispatch): blocks [0,1536) split x into hi/lo
// planes; blocks [1536,1968) transpose+split qkv_w.
// ---------------------------------------------------------------------------
__global__ __launch_bounds__(256) void conv_all(
    const float* __restrict__ X, u16* __restrict__ Xh, u16* __restrict__ Xl,
    const float* __restrict__ W, u16* __restrict__ Wt_h, u16* __restrict__ Wt_l)
{
    __shared__ float Ts[64][65];
    const int bid = blockIdx.x;
    const int t   = threadIdx.x;

    if (bid < 1536) {
        const size_t off = ((size_t)bid * 256 + t) * 8;
        float4 a = *(const float4*)&X[off];
        float4 b = *(const float4*)&X[off + 4];
        float v[8] = {a.x, a.y, a.z, a.w, b.x, b.y, b.z, b.w};
        u16 hb[8], lb[8];
        #pragma unroll
        for (int i = 0; i < 8; ++i) {
            u16 hi = f2bf(v[i]);
            hb[i] = hi;
            lb[i] = f2bf(v[i] - bf2f(hi));
        }
        *(bf16x8*)&Xh[off] = *(const bf16x8*)&hb[0];
        *(bf16x8*)&Xl[off] = *(const bf16x8*)&lb[0];
    } else {
        const int wb = bid - 1536;        // 0..431 = 36 xt x 12 yt
        const int n0 = (wb % 36) * 64, k0 = (wb / 36) * 64;
        const int r  = t >> 2;
        const int cq = (t & 3) * 16;

        #pragma unroll
        for (int q = 0; q < 4; ++q) {
            float4 v = *(const float4*)&W[(size_t)(k0 + r) * 2304 + n0 + cq + q * 4];
            Ts[r][cq + q * 4 + 0] = v.x;
            Ts[r][cq + q * 4 + 1] = v.y;
            Ts[r][cq + q * 4 + 2] = v.z;
            Ts[r][cq + q * 4 + 3] = v.w;
        }
        __syncthreads();
        u16 hb[16], lb[16];
        #pragma unroll
        for (int i = 0; i < 16; ++i) {
            float val = Ts[cq + i][r];
            u16 hi = f2bf(val);
            hb[i] = hi;
            lb[i] = f2bf(val - bf2f(hi));
        }
        const size_t obase = (size_t)(n0 + r) * 768 + k0 + cq;
        *(bf16x8*)&Wt_h[obase]     = *(const bf16x8*)&hb[0];
        *(bf16x8*)&Wt_h[obase + 8] = *(const bf16x8*)&hb[8];
        *(bf16x8*)&Wt_l[obase]     = *(const bf16x8*)&lb[0];
        *(bf16x8*)&Wt_l[obase + 8] = *(const bf16x8*)&lb[8];
    }
}

// ---------------------------------------------------------------------------
// Weight convert: W f32 [K][Ncols] -> Wt_h, Wt_l bf16 [Ncols][K] transposed.
// ---------------------------------------------------------------------------
__global__ __launch_bounds__(256) void conv_w_nt(
    const float* __restrict__ W, u16* __restrict__ Wt_h, u16* __restrict__ Wt_l,
    int Kdim, int Ncols)
{
    __shared__ float Ts[64][65];
    const int t  = threadIdx.x;
    const int r  = t >> 2;
    const int cq = (t & 3) * 16;
    const int n0 = blockIdx.x * 64, k0 = blockIdx.y * 64;

    #pragma unroll
    for (int q = 0; q < 4; ++q) {
        float4 v = *(const float4*)&W[(size_t)(k0 + r) * Ncols + n0 + cq + q * 4];
        Ts[r][cq + q * 4 + 0] = v.x;
        Ts[r][cq + q * 4 + 1] = v.y;
        Ts[r][cq + q * 4 + 2] = v.z;
        Ts[r][cq + q * 4 + 3] = v.w;
    }
    __syncthreads();
    u16 hb[16], lb[16];
    #pragma unroll
    for (int i = 0; i < 16; ++i) {
        float val = Ts[cq + i][r];
        u16 hi = f2bf(val);
        hb[i] = hi;
        lb[i] = f2bf(val - bf2f(hi));
    }
    const size_t obase = (size_t)(n0 + r) * Kdim + k0 + cq;
    *(bf16x8*)&Wt_h[obase]     = *(const bf16x8*)&hb[0];
    *(bf16x8*)&Wt_h[obase + 8] = *(const bf16x8*)&hb[8];
    *(bf16x8*)&Wt_l[obase]     = *(const bf16x8*)&lb[0];
    *(bf16x8*)&Wt_l[obase + 8] = *(const bf16x8*)&lb[8];
}

// ---------------------------------------------------------------------------
// qkv GEMM: 128x128 tile, pure-plane NT, global_load_lds staging with
// COUNTED-vmcnt depth-1 double buffer, XCD swizzle, LDS-transposed epilogue.
// ---------------------------------------------------------------------------
__global__ __launch_bounds__(256) void gemm_qkv(
    const u16* __restrict__ Ath, const u16* __restrict__ Atl,
    const u16* __restrict__ Bth, const u16* __restrict__ Btl,
    const float* __restrict__ bias,
    u16* __restrict__ Ch, u16* __restrict__ Cl, float* __restrict__ Vf)
{
    __shared__ __align__(16) char smem[65536];   // 2 x 32KB staging buffers

    const int t    = threadIdx.x;
    // XCD swizzle: grid(576); 9 x-tiles x 8 y-tiles per XCD
    const int d    = blockIdx.x;
    const int xcd  = d & 7, j = d >> 3;
    const int xt   = (xcd & 1) * 9 + (j % 9);
    const int yt   = (xcd >> 1) * 8 + (j / 9);
    const int m0   = yt * 128, n0 = xt * 128;
    const int lane = t & 63, w = t >> 6;
    const int wm   = (w >> 1) * 64, wn = (w & 1) * 64;
    const int fr   = lane & 15, kg8 = lane >> 4;
    const int w16  = w * 16;
    const int r4s  = lane >> 2, q4s = (lane & 3) * 8;

    auto stage = [&](int k0, int buf) {
        char* base = smem + buf * 32768;
        u16* Ah = (u16*)(base);
        u16* Al = (u16*)(base + 8192);
        u16* Bh = (u16*)(base + 16384);
        u16* Bl = (u16*)(base + 24576);
        const size_t ga0 = (size_t)(m0 + w16 + r4s) * C_ + k0 + q4s;
        const size_t ga1 = ga0 + (size_t)64 * C_;
        const size_t gb0 = (size_t)(n0 + w16 + r4s) * C_ + k0 + q4s;
        const size_t gb1 = gb0 + (size_t)64 * C_;
        gll16(&Ath[ga0], &Ah[w16 * LDN_]);
        gll16(&Ath[ga1], &Ah[(64 + w16) * LDN_]);
        gll16(&Atl[ga0], &Al[w16 * LDN_]);
        gll16(&Atl[ga1], &Al[(64 + w16) * LDN_]);
        gll16(&Bth[gb0], &Bh[w16 * LDN_]);
        gll16(&Bth[gb1], &Bh[(64 + w16) * LDN_]);
        gll16(&Btl[gb0], &Bl[w16 * LDN_]);
        gll16(&Btl[gb1], &Bl[(64 + w16) * LDN_]);
    };

    f32x4 acc[4][4];
    #pragma unroll
    for (int i = 0; i < 4; ++i)
        #pragma unroll
        for (int j2 = 0; j2 < 4; ++j2)
            acc[i][j2] = (f32x4){0.f, 0.f, 0.f, 0.f};

    stage(0, 0);                          // 8 loads in flight
    for (int kt = 0; kt < 24; ++kt) {
        if (kt < 23) {
            asm volatile("s_waitcnt lgkmcnt(0)" ::: "memory");
            __builtin_amdgcn_s_barrier();
            __builtin_amdgcn_sched_barrier(0);
            stage((kt + 1) * 32, (kt + 1) & 1);          // +8 -> 16 in flight
            asm volatile("s_waitcnt vmcnt(8)" ::: "memory"); // stage(kt) done
        } else {
            asm volatile("s_waitcnt vmcnt(0)" ::: "memory");
        }
        __builtin_amdgcn_s_barrier();     // all waves' stage(kt) visible
        __builtin_amdgcn_sched_barrier(0);

        char* base = smem + (kt & 1) * 32768;
        u16* Ah = (u16*)(base);
        u16* Al = (u16*)(base + 8192);
        u16* Bh = (u16*)(base + 16384);
        u16* Bl = (u16*)(base + 24576);

        bf16x8 aF[4], bF[4], a2F[4], b2F[4];
        #pragma unroll
        for (int fm = 0; fm < 4; ++fm)
            aF[fm] = *(const bf16x8*)&Ah[(wm + fm * 16 + fr) * LDN_ + kg8 * 8];
        #pragma unroll
        for (int fn = 0; fn < 4; ++fn)
            bF[fn] = *(const bf16x8*)&Bh[(wn + fn * 16 + fr) * LDN_ + kg8 * 8];
        #pragma unroll
        for (int fm = 0; fm < 4; ++fm)
            #pragma unroll
            for (int fn = 0; fn < 4; ++fn)
                acc[fm][fn] = __builtin_amdgcn_mfma_f32_16x16x32_bf16(
                    aF[fm], bF[fn], acc[fm][fn], 0, 0, 0);
        #pragma unroll
        for (int fn = 0; fn < 4; ++fn)
            b2F[fn] = *(const bf16x8*)&Bl[(wn + fn * 16 + fr) * LDN_ + kg8 * 8];
        #pragma unroll
        for (int fm = 0; fm < 4; ++fm)
            #pragma unroll
            for (int fn = 0; fn < 4; ++fn)
                acc[fm][fn] = __builtin_amdgcn_mfma_f32_16x16x32_bf16(
                    aF[fm], b2F[fn], acc[fm][fn], 0, 0, 0);
        #pragma unroll
        for (int fm = 0; fm < 4; ++fm)
            a2F[fm] = *(const bf16x8*)&Al[(wm + fm * 16 + fr) * LDN_ + kg8 * 8];
        #pragma unroll
        for (int fm = 0; fm < 4; ++fm)
            #pragma unroll
            for (int fn = 0; fn < 4; ++fn)
                acc[fm][fn] = __builtin_amdgcn_mfma_f32_16x16x32_bf16(
                    a2F[fm], bF[fn], acc[fm][fn], 0, 0, 0);
    }
    __syncthreads();   // full drain; staging LDS reusable for epilogue

    // Epilogue: per-wave LDS transpose -> coalesced vector stores.
    const bool isV = (n0 >= 1536);
    float* Ts = (float*)(smem + w * 8448);   // 32 x 66 f32 per wave
    const int lr8 = lane >> 3, lc8 = (lane & 7) * 8;
    #pragma unroll
    for (int p = 0; p < 2; ++p) {
        #pragma unroll
        for (int fmh = 0; fmh < 2; ++fmh) {
            const int fm = p * 2 + fmh;
            #pragma unroll
            for (int fn = 0; fn < 4; ++fn) {
                const float bv = bias[n0 + wn + fn * 16 + fr];
                #pragma unroll
                for (int i = 0; i < 4; ++i)
                    Ts[(fmh * 16 + kg8 * 4 + i) * 66 + fn * 16 + fr] =
                        acc[fm][fn][i] + bv;
            }
        }
        #pragma unroll
        for (int it = 0; it < 4; ++it) {
            const int r = it * 8 + lr8;
            float v[8];
            #pragma unroll
            for (int c = 0; c < 8; ++c) v[c] = Ts[r * 66 + lc8 + c];
            const int grow = m0 + wm + p * 32 + r;
            const int gcol = n0 + wn + lc8;
            if (isV) {
                float4 v0 = {v[0], v[1], v[2], v[3]};
                float4 v1 = {v[4], v[5], v[6], v[7]};
                float* vp = &Vf[(size_t)grow * C_ + gcol - 1536];
                *(float4*)vp       = v0;
                *(float4*)(vp + 4) = v1;
            } else {
                u16 hb[8], lb[8];
                #pragma unroll
                for (int c = 0; c < 8; ++c) {
                    u16 hi = f2bf(v[c]);
                    hb[c] = hi;
                    lb[c] = f2bf(v[c] - bf2f(hi));
                }
                *(bf16x8*)&Ch[(size_t)grow * QKS_ + gcol] = *(const bf16x8*)&hb[0];
                *(bf16x8*)&Cl[(size_t)grow * QKS_ + gcol] = *(const bf16x8*)&lb[0];
            }
        }
    }
}

// ---------------------------------------------------------------------------
// Fused z + per-head partial softmax, T14 async-stage pipelined over heads.
// Unstabilized softmax (scores O(1)), fast __expf/__logf.
// ---------------------------------------------------------------------------
__global__ __launch_bounds__(256) void attn_fused(
    const u16* __restrict__ qh, const u16* __restrict__ ql,
    const float* __restrict__ u, float* __restrict__ z,
    float2* __restrict__ mlp)
{
    __shared__ u16 KsH[128 * LK_], KsL[128 * LK_];

    const int t    = threadIdx.x;
    const int lane = t & 63, w = t >> 6;
    const int fr   = lane & 15, kg8 = lane >> 4;
    const int n0   = blockIdx.x * 64;
    const int m0   = blockIdx.y * 128;
    const int mc   = blockIdx.y;
    const int b    = blockIdx.z;

    f32x4 zacc[8];
    #pragma unroll
    for (int fn = 0; fn < 8; ++fn) zacc[fn] = (f32x4){0.f, 0.f, 0.f, 0.f};

    const int skr = t >> 1, skd = (t & 1) * 32;

    bf16x8 kAr[8], kBr[8], qAr[4], qBr[4];

    auto loadK = [&](bf16x8 (&kr)[8], int hd) {
        const size_t kb = (size_t)(b * N_ + m0 + skr) * QKS_ + 768 + hd * 64 + skd;
        kr[0] = *(const bf16x8*)&qh[kb];
        kr[1] = *(const bf16x8*)&qh[kb + 8];
        kr[2] = *(const bf16x8*)&qh[kb + 16];
        kr[3] = *(const bf16x8*)&qh[kb + 24];
        kr[4] = *(const bf16x8*)&ql[kb];
        kr[5] = *(const bf16x8*)&ql[kb + 8];
        kr[6] = *(const bf16x8*)&ql[kb + 16];
        kr[7] = *(const bf16x8*)&ql[kb + 24];
    };
    auto loadQ = [&](bf16x8 (&qr)[4], int hd) {
        const size_t qb = (size_t)(b * N_ + n0 + w * 16 + fr) * QKS_ + hd * 64 + kg8 * 8;
        qr[0] = *(const bf16x8*)&qh[qb];
        qr[1] = *(const bf16x8*)&qh[qb + 32];
        qr[2] = *(const bf16x8*)&ql[qb];
        qr[3] = *(const bf16x8*)&ql[qb + 32];
    };
    auto writeK = [&](const bf16x8 (&kr)[8]) {
        const int sb = skr * LK_ + skd;
        *(bf16x8*)&KsH[sb]      = kr[0];  *(bf16x8*)&KsH[sb + 8]  = kr[1];
        *(bf16x8*)&KsH[sb + 16] = kr[2];  *(bf16x8*)&KsH[sb + 24] = kr[3];
        *(bf16x8*)&KsL[sb]      = kr[4];  *(bf16x8*)&KsL[sb + 8]  = kr[5];
        *(bf16x8*)&KsL[sb + 16] = kr[6];  *(bf16x8*)&KsL[sb + 24] = kr[7];
    };
    auto compute = [&](const bf16x8 (&qr)[4], int hd) {
        f32x4 acc[8];
        #pragma unroll
        for (int fn = 0; fn < 8; ++fn) acc[fn] = (f32x4){0.f, 0.f, 0.f, 0.f};
        #pragma unroll
        for (int fn = 0; fn < 8; ++fn) {
            const int bidx = (fn * 16 + fr) * LK_ + kg8 * 8;
            bf16x8 bH = *(const bf16x8*)&KsH[bidx];
            bf16x8 bL = *(const bf16x8*)&KsL[bidx];
            acc[fn] = __builtin_amdgcn_mfma_f32_16x16x32_bf16(qr[0], bH, acc[fn], 0, 0, 0);
            acc[fn] = __builtin_amdgcn_mfma_f32_16x16x32_bf16(qr[0], bL, acc[fn], 0, 0, 0);
            acc[fn] = __builtin_amdgcn_mfma_f32_16x16x32_bf16(qr[2], bH, acc[fn], 0, 0, 0);
        }
        #pragma unroll
        for (int fn = 0; fn < 8; ++fn) {
            const int bidx = (fn * 16 + fr) * LK_ + 32 + kg8 * 8;
            bf16x8 bH = *(const bf16x8*)&KsH[bidx];
            bf16x8 bL = *(const bf16x8*)&KsL[bidx];
            acc[fn] = __builtin_amdgcn_mfma_f32_16x16x32_bf16(qr[1], bH, acc[fn], 0, 0, 0);
            acc[fn] = __builtin_amdgcn_mfma_f32_16x16x32_bf16(qr[1], bL, acc[fn], 0, 0, 0);
            acc[fn] = __builtin_amdgcn_mfma_f32_16x16x32_bf16(qr[3], bH, acc[fn], 0, 0, 0);
        }
        #pragma unroll
        for (int fn = 0; fn < 8; ++fn) {
            zacc[fn][0] += acc[fn][0];
            zacc[fn][1] += acc[fn][1];
            zacc[fn][2] += acc[fn][2];
            zacc[fn][3] += acc[fn][3];
        }
        #pragma unroll
        for (int reg = 0; reg < 4; ++reg) {
            float tsum = 0.f;
            #pragma unroll
            for (int fn = 0; fn < 8; ++fn)
                tsum += __expf(acc[fn][reg] * 0.125f);
            tsum += __shfl_xor(tsum, 1);
            tsum += __shfl_xor(tsum, 2);
            tsum += __shfl_xor(tsum, 4);
            tsum += __shfl_xor(tsum, 8);
            if (fr == 0) {
                const int n = n0 + w * 16 + kg8 * 4 + reg;
                mlp[(((size_t)(b * H_ + hd)) * N_ + n) * 8 + mc] =
                    make_float2(0.f, tsum);
            }
        }
    };

    loadQ(qAr, 0);
    loadK(kAr, 0);
    for (int hp = 0; hp < 6; ++hp) {
        const int hd0 = hp * 2, hd1 = hp * 2 + 1;
        __syncthreads();
        writeK(kAr);
        __syncthreads();
        loadQ(qBr, hd1);
        loadK(kBr, hd1);
        compute(qAr, hd0);
        __syncthreads();
        writeK(kBr);
        __syncthreads();
        if (hp < 5) {
            loadQ(qAr, hd0 + 2);
            loadK(kAr, hd0 + 2);
        }
        compute(qBr, hd1);
    }

    const float sc = 0.125f / 12.0f;
    #pragma unroll
    for (int fn = 0; fn < 8; ++fn) {
        const int m = m0 + fn * 16 + fr;
        #pragma unroll
        for (int reg = 0; reg < 4; ++reg) {
            const int n = n0 + w * 16 + kg8 * 4 + reg;
            const float uv = u[((size_t)(b * N_ + n)) * N_ + m];
            const float g  = -__logf(-__logf(uv + EPS_) + EPS_);
            z[((size_t)(b * N_ + n)) * N_ + m] = zacc[fn][reg] * sc + g;
        }
    }
}

// ---------------------------------------------------------------------------
// Merge 8 per-chunk partial sums into final (m=0, l) per (b,h,n).
// ---------------------------------------------------------------------------
__global__ __launch_bounds__(256) void ml_merge(
    const float2* __restrict__ mlp, float2* __restrict__ ml)
{
    const size_t idx = (size_t)blockIdx.x * 256 + threadIdx.x;
    float l = 0.f;
    #pragma unroll
    for (int i = 0; i < 8; ++i) l += mlp[idx * 8 + i].y;
    ml[idx] = make_float2(0.f, l);
}

// ---------------------------------------------------------------------------
// Per row: exact 32nd-largest of z; emit all cols >= thresh (cap 62).
// ---------------------------------------------------------------------------
__global__ __launch_bounds__(64) void topk_cols_kernel(
    const float* __restrict__ z, TopkRec* __restrict__ recs)
{
    const int row  = blockIdx.x;
    const int lane = threadIdx.x;
    const float* zr = z + (size_t)row * N_;
    float zv[16], wk[16];
    #pragma unroll
    for (int j = 0; j < 16; ++j) { zv[j] = zr[lane + 64 * j]; wk[j] = zv[j]; }

    float thresh = -INFINITY;
    for (int it = 0; it < TOPK_; ++it) {
        float lm = wk[0]; int li = 0;
        #pragma unroll
        for (int j = 1; j < 16; ++j)
            if (wk[j] > lm) { lm = wk[j]; li = j; }
        float gm = lm;
        gm = fmaxf(gm, __shfl_xor(gm, 1));
        gm = fmaxf(gm, __shfl_xor(gm, 2));
        gm = fmaxf(gm, __shfl_xor(gm, 4));
        gm = fmaxf(gm, __shfl_xor(gm, 8));
        gm = fmaxf(gm, __shfl_xor(gm, 16));
        gm = fmaxf(gm, __shfl_xor(gm, 32));
        unsigned long long has = __ballot(lm == gm);
        int first = __ffsll((unsigned long long)has) - 1;
        if (lane == first) wk[li] = -INFINITY;
        thresh = gm;
    }

    const unsigned long long below = ((unsigned long long)1 << lane) - 1;
    unsigned int basec = 0;
    TopkRec* rec = recs + row;
    #pragma unroll
    for (int j = 0; j < 16; ++j) {
        unsigned long long wmask = __ballot(zv[j] >= thresh);
        if (zv[j] >= thresh) {
            unsigned int pos = basec + (unsigned int)__popcll(wmask & below);
            if (pos < 62u) rec->c[pos] = (unsigned short)(lane + 64 * j);
        }
        basec += (unsigned int)__popcll(wmask);
    }
    if (lane == 0) rec->cnt = basec > 62u ? 62u : basec;
}

// ---------------------------------------------------------------------------
// Pass B: sparse gather numerator. Lane = (c,dq). V read as f32.
// Batch-pair ILP + XCD-locality swizzle (round-18 proven version).
// ---------------------------------------------------------------------------
__global__ __launch_bounds__(256) void sparse_pv_kernel(
    const u16* __restrict__ qh, const u16* __restrict__ ql,
    const float* __restrict__ Vf,
    const TopkRec* __restrict__ recs, const float2* __restrict__ ml,
    const float* __restrict__ head_scores,
    u16* __restrict__ out1h, u16* __restrict__ out1l)
{
    __shared__ int cols_s[62];
    __shared__ int cnt_s;

    const int t    = threadIdx.x;
    const int lane = t & 63, wv = t >> 6;
    const int c4   = lane >> 2;
    const int dq   = lane & 3;
    // XCD-locality: d -> (b, n) so batch b lands on XCDs {2b, 2b+1}
    const int d    = blockIdx.x;
    const int xcd  = d & 7;
    const int b    = xcd >> 1;
    const int n    = (xcd & 1) * 512 + (d >> 3);
    const int row  = b * N_ + n;

    const TopkRec* rec = recs + row;
    if (t == 0) cnt_s = (int)min(rec->cnt, 62u);
    if (t < 62) cols_s[t] = rec->c[t];

    float hsum = 0.f;
    #pragma unroll
    for (int i = 0; i < H_; ++i) hsum += head_scores[i];
    const float hs_mean = hsum * (1.0f / 12.0f);
    __syncthreads();
    const int cnt = cnt_s;
    const int nbatch = (cnt + 15) >> 4;

    for (int hd = wv; hd < H_; hd += 4) {
        float qv[16];
        {
            const size_t qb = (size_t)row * QKS_ + hd * 64 + dq * 16;
            bf16x8 qh0 = *(const bf16x8*)&qh[qb], qh1 = *(const bf16x8*)&qh[qb + 8];
            bf16x8 ql0 = *(const bf16x8*)&ql[qb], ql1 = *(const bf16x8*)&ql[qb + 8];
            #pragma unroll
            for (int i = 0; i < 8; ++i) {
                qv[i]     = bf2f((u16)qh0[i]) + bf2f((u16)ql0[i]);
                qv[i + 8] = bf2f((u16)qh1[i]) + bf2f((u16)ql1[i]);
            }
        }
        const float2 mlv = ml[((size_t)(b * H_ + hd)) * N_ + n];

        float acc[16];
        #pragma unroll
        for (int i = 0; i < 16; ++i) acc[i] = 0.f;

        for (int j0 = 0; j0 < nbatch; j0 += 2) {
            const int cidx0 = j0 * 16 + c4;
            const int cidx1 = cidx0 + 16;
            const bool v0 = (cidx0 < cnt);
            const bool v1 = (cidx1 < cnt);
            const int col0 = cols_s[v0 ? cidx0 : 0];
            const int col1 = cols_s[v1 ? cidx1 : 0];

            const size_t kb0 = (size_t)(b * N_ + col0) * QKS_ + 768 + hd * 64 + dq * 16;
            const size_t kb1 = (size_t)(b * N_ + col1) * QKS_ + 768 + hd * 64 + dq * 16;
            bf16x8 kh00 = *(const bf16x8*)&qh[kb0], kh01 = *(const bf16x8*)&qh[kb0 + 8];
            bf16x8 kl00 = *(const bf16x8*)&ql[kb0], kl01 = *(const bf16x8*)&ql[kb0 + 8];
            bf16x8 kh10 = *(const bf16x8*)&qh[kb1], kh11 = *(const bf16x8*)&qh[kb1 + 8];
            bf16x8 kl10 = *(const bf16x8*)&ql[kb1], kl11 = *(const bf16x8*)&ql[kb1 + 8];
            const float* vb0 = &Vf[(size_t)(b * N_ + col0) * C_ + hd * 64 + dq * 16];
            const float* vb1 = &Vf[(size_t)(b * N_ + col1) * C_ + hd * 64 + dq * 16];
            float4 va0[4], va1[4];
            #pragma unroll
            for (int q = 0; q < 4; ++q) {
                va0[q] = *(const float4*)&vb0[q * 4];
                va1[q] = *(const float4*)&vb1[q * 4];
            }

            float dot0 = 0.f, dot1 = 0.f;
            #pragma unroll
            for (int i = 0; i < 8; ++i) {
                dot0 += qv[i]     * (bf2f((u16)kh00[i]) + bf2f((u16)kl00[i]));
                dot1 += qv[i]     * (bf2f((u16)kh10[i]) + bf2f((u16)kl10[i]));
                dot0 += qv[i + 8] * (bf2f((u16)kh01[i]) + bf2f((u16)kl01[i]));
                dot1 += qv[i + 8] * (bf2f((u16)kh11[i]) + bf2f((u16)kl11[i]));
            }
            dot0 += __shfl_xor(dot0, 1);
            dot1 += __shfl_xor(dot1, 1);
            dot0 += __shfl_xor(dot0, 2);
            dot1 += __shfl_xor(dot1, 2);
            const float p0 = v0 ? __expf(dot0 * 0.125f) : 0.f;
            const float p1 = v1 ? __expf(dot1 * 0.125f) : 0.f;

            #pragma unroll
            for (int q = 0; q < 4; ++q) {
                acc[q * 4 + 0] += p0 * va0[q].x + p1 * va1[q].x;
                acc[q * 4 + 1] += p0 * va0[q].y + p1 * va1[q].y;
                acc[q * 4 + 2] += p0 * va0[q].z + p1 * va1[q].z;
                acc[q * 4 + 3] += p0 * va0[q].w + p1 * va1[q].w;
            }
        }

        #pragma unroll
        for (int dd = 4; dd < 64; dd <<= 1)
            #pragma unroll
            for (int i = 0; i < 16; ++i)
                acc[i] += __shfl_xor(acc[i], dd);

        if (c4 == 0) {
            const float s = hs_mean / mlv.y;
            u16 hb[16], lb[16];
            #pragma unroll
            for (int i = 0; i < 16; ++i) {
                float val = acc[i] * s;
                u16 hi = f2bf(val);
                hb[i] = hi;
                lb[i] = f2bf(val - bf2f(hi));
            }
            const size_t ob = (size_t)row * C_ + hd * 64 + dq * 16;
            *(bf16x8*)&out1h[ob]     = *(const bf16x8*)&hb[0];
            *(bf16x8*)&out1h[ob + 8] = *(const bf16x8*)&hb[8];
            *(bf16x8*)&out1l[ob]     = *(const bf16x8*)&lb[0];
            *(bf16x8*)&out1l[ob + 8] = *(const bf16x8*)&lb[8];
        }
    }
}

// ---------------------------------------------------------------------------
// proj GEMM: 64x128 tile (grid 384), pure-plane NT, counted-vmcnt depth-1
// double buffer, XCD swizzle, LDS-transposed coalesced f32 epilogue.
// ---------------------------------------------------------------------------
__global__ __launch_bounds__(256) void gemm_proj(
    const u16* __restrict__ Ath, const u16* __restrict__ Atl,
    const u16* __restrict__ Bth, const u16* __restrict__ Btl,
    const float* __restrict__ bias, float* __restrict__ Cm)
{
    __shared__ __align__(16) char smem[49152];   // 2 x 24KB staging buffers

    const int t    = threadIdx.x;
    // XCD swizzle: grid(384) = 6 xt x 64 yt; per XCD 6x x 8y
    const int d    = blockIdx.x;
    const int xcd  = d & 7, j = d >> 3;
    const int xt   = j % 6;
    const int yt   = xcd * 8 + j / 6;
    const int m0   = yt * 64, n0 = xt * 128;
    const int lane = t & 63, w = t >> 6;
    const int wm   = (w & 1) * 32, wn = (w >> 1) * 64;
    const int fr   = lane & 15, kg8 = lane >> 4;
    const int w16  = w * 16;
    const int r4s  = lane >> 2, q4s = (lane & 3) * 8;

    auto stage = [&](int k0, int buf) {
        char* base = smem + buf * 24576;
        u16* Ah = (u16*)(base);
        u16* Al = (u16*)(base + 4096);
        u16* Bh = (u16*)(base + 8192);
        u16* Bl = (u16*)(base + 16384);
        const size_t ga  = (size_t)(m0 + w16 + r4s) * C_ + k0 + q4s;
        const size_t gb0 = (size_t)(n0 + w * 32 + r4s) * C_ + k0 + q4s;
        const size_t gb1 = gb0 + (size_t)16 * C_;
        gll16(&Ath[ga],  &Ah[w16 * LDN_]);
        gll16(&Atl[ga],  &Al[w16 * LDN_]);
        gll16(&Bth[gb0], &Bh[(w * 32) * LDN_]);
        gll16(&Bth[gb1], &Bh[(w * 32 + 16) * LDN_]);
        gll16(&Btl[gb0], &Bl[(w * 32) * LDN_]);
        gll16(&Btl[gb1], &Bl[(w * 32 + 16) * LDN_]);
    };

    f32x4 acc[2][4];
    #pragma unroll
    for (int i = 0; i < 2; ++i)
        #pragma unroll
        for (int j2 = 0; j2 < 4; ++j2)
            acc[i][j2] = (f32x4){0.f, 0.f, 0.f, 0.f};

    stage(0, 0);
    for (int kt = 0; kt < 24; ++kt) {
        if (kt < 23) {
            asm volatile("s_waitcnt lgkmcnt(0)" ::: "memory");
            __builtin_amdgcn_s_barrier();
            __builtin_amdgcn_sched_barrier(0);
            stage((kt + 1) * 32, (kt + 1) & 1);
            asm volatile("s_waitcnt vmcnt(6)" ::: "memory");
        } else {
            asm volatile("s_waitcnt vmcnt(0)" ::: "memory");
        }
        __builtin_amdgcn_s_barrier();
        __builtin_amdgcn_sched_barrier(0);

        char* base = smem + (kt & 1) * 24576;
        u16* Ah = (u16*)(base);
        u16* Al = (u16*)(base + 4096);
        u16* Bh = (u16*)(base + 8192);
        u16* Bl = (u16*)(base + 16384);

        bf16x8 aF[2], bF[4], a2F[2], b2F[4];
        #pragma unroll
        for (int fm = 0; fm < 2; ++fm)
            aF[fm] = *(const bf16x8*)&Ah[(wm + fm * 16 + fr) * LDN_ + kg8 * 8];
        #pragma unroll
        for (int fn = 0; fn < 4; ++fn)
            bF[fn] = *(const bf16x8*)&Bh[(wn + fn * 16 + fr) * LDN_ + kg8 * 8];
        #pragma unroll
        for (int fm = 0; fm < 2; ++fm)
            #pragma unroll
            for (int fn = 0; fn < 4; ++fn)
                acc[fm][fn] = __builtin_amdgcn_mfma_f32_16x16x32_bf16(
                    aF[fm], bF[fn], acc[fm][fn], 0, 0, 0);
        #pragma unroll
        for (int fn = 0; fn < 4; ++fn)
            b2F[fn] = *(const bf16x8*)&Bl[(wn + fn * 16 + fr) * LDN_ + kg8 * 8];
        #pragma unroll
        for (int fm = 0; fm < 2; ++fm)
            #pragma unroll
            for (int fn = 0; fn < 4; ++fn)
                acc[fm][fn] = __builtin_amdgcn_mfma_f32_16x16x32_bf16(
                    aF[fm], b2F[fn], acc[fm][fn], 0, 0, 0);
        #pragma unroll
        for (int fm = 0; fm < 2; ++fm)
            a2F[fm] = *(const bf16x8*)&Al[(wm + fm * 16 + fr) * LDN_ + kg8 * 8];
        #pragma unroll
        for (int fm = 0; fm < 2; ++fm)
            #pragma unroll
            for (int fn = 0; fn < 4; ++fn)
                acc[fm][fn] = __builtin_amdgcn_mfma_f32_16x16x32_bf16(
                    a2F[fm], bF[fn], acc[fm][fn], 0, 0, 0);
    }
    __syncthreads();

    float* Ts = (float*)(smem + w * 8448);
    const int lr8 = lane >> 3, lc8 = (lane & 7) * 8;
    #pragma unroll
    for (int fm = 0; fm < 2; ++fm)
        #pragma unroll
        for (int fn = 0; fn < 4; ++fn) {
            const float bv = bias[n0 + wn + fn * 16 + fr];
            #pragma unroll
            for (int i = 0; i < 4; ++i)
                Ts[(fm * 16 + kg8 * 4 + i) * 66 + fn * 16 + fr] =
                    acc[fm][fn][i] + bv;
        }
    #pragma unroll
    for (int it = 0; it < 4; ++it) {
        const int r = it * 8 + lr8;
        float v[8];
        #pragma unroll
        for (int c = 0; c < 8; ++c) v[c] = Ts[r * 66 + lc8 + c];
        const int grow = m0 + wm + r;
        const int gcol = n0 + wn + lc8;
        float4 v0 = {v[0], v[1], v[2], v[3]};
        float4 v1 = {v[4], v[5], v[6], v[7]};
        float* cp = &Cm[(size_t)grow * C_ + gcol];
        *(float4*)cp       = v0;
        *(float4*)(cp + 4) = v1;
    }
}

// ---------------------------------------------------------------------------
extern "C" void kernel_launch(void* const* d_in, const int* in_sizes, int n_in,
                              void* d_out, int out_size, void* d_ws, size_t ws_size,
                              hipStream_t stream)
{
    (void)in_sizes; (void)n_in; (void)out_size; (void)ws_size;
    const float* x           = (const float*)d_in[0];
    const float* u           = (const float*)d_in[1];
    const float* qkv_w       = (const float*)d_in[2];
    const float* qkv_b       = (const float*)d_in[3];
    const float* proj_w      = (const float*)d_in[4];
    const float* proj_b      = (const float*)d_in[5];
    const float* head_scores = (const float*)d_in[6];
    float* out = (float*)d_out;

    // Workspace (proven 55,050,240-byte footprint):
    //   [0, 12582912)            qkv_h  bf16 [4096][1536]  (Q,K planes)
    //   [12582912, 25165824)     qkv_l
    //   [25165824, 37748736)     V f32 [4096][768]
    //   R = [37748736, 55050240), time-shared:
    //     phase1: wq_t_h | wq_t_l (dead after gemm_qkv)
    //     phase2: z f32 [0,16777216) + recs [16777216,17301504)
    //     phase3 (z dead): wp_t_h | wp_t_l | ml | out1_h | out1_l
    // d_out (12,582,912 B) time-shared:
    //     x_h | x_l planes (dead after gemm_qkv)
    //     mlp partials [0, 3145728); gemm_proj overwrites d_out last.
    char* ws = (char*)d_ws;
    u16*     qkv_h  = (u16*)ws;
    u16*     qkv_l  = (u16*)(ws + 12582912);
    float*   Vf     = (float*)(ws + 25165824);
    char*    R      = ws + 37748736;
    u16*     wq_t_h = (u16*)R;
    u16*     wq_t_l = (u16*)(R + 3538944);
    float*   z      = (float*)R;
    TopkRec* recs   = (TopkRec*)(R + 16777216);
    u16*     wp_t_h = (u16*)R;
    u16*     wp_t_l = (u16*)(R + 1179648);
    float2*  ml     = (float2*)(R + 2359296);
    u16*     out1h  = (u16*)(R + 2752512);
    u16*     out1l  = (u16*)(R + 9043968);
    u16*     x_h    = (u16*)d_out;
    u16*     x_l    = (u16*)((char*)d_out + 6291456);
    float2*  mlp    = (float2*)d_out;

    // 0+1) fused: pre-split x AND convert qkv_w (one dispatch)
    conv_all<<<dim3(1968), dim3(256), 0, stream>>>(
        x, x_h, x_l, qkv_w, wq_t_h, wq_t_l);

    // 2) qkv = x @ qkv_w + b  -> Q,K planes + V f32 (counted-vmcnt dbuf)
    gemm_qkv<<<dim3(576), dim3(256), 0, stream>>>(
        x_h, x_l, wq_t_h, wq_t_l, qkv_b, qkv_h, qkv_l, Vf);

    // 3) fused: z (+gumbel) AND per-head per-chunk softmax partials
    attn_fused<<<dim3(16, 8, B_), dim3(256), 0, stream>>>(
        qkv_h, qkv_l, u, z, mlp);

    // 4) exact top-32 -> column records
    topk_cols_kernel<<<dim3(B_ * N_), dim3(64), 0, stream>>>(z, recs);

    // 5) convert proj_w -> transposed split planes [768][768]  (z dead)
    conv_w_nt<<<dim3(768 / 64, 768 / 64), dim3(256), 0, stream>>>(
        proj_w, wp_t_h, wp_t_l, 768, 768);

    // 6) merge partials -> final (m=0, l)
    ml_merge<<<dim3(B_ * H_ * N_ / 256), dim3(256), 0, stream>>>(mlp, ml);

    // 7) sparse gather numerator -> out1 planes (batch-pair ILP + XCD-local)
    sparse_pv_kernel<<<dim3(B_ * N_), dim3(256), 0, stream>>>(
        qkv_h, qkv_l, Vf, recs, ml, head_scores, out1h, out1l);

    // 8) out = out1 @ proj_w + b  (counted-vmcnt dbuf)
    gemm_proj<<<dim3(384), dim3(256), 0, stream>>>(
        out1h, out1l, wp_t_h, wp_t_l, proj_b, out);
}